// Round 8
// baseline (161.353 us; speedup 1.0000x reference)
//
#include <hip/hip_runtime.h>
#include <hip/hip_bf16.h>

// Problem constants (from reference setup_inputs)
#define S_SCENES 512
#define P_PED    128
#define G_GRP    16
#define D_IN     256
#define D_HID    512
#define D_OUT    16
#define D_FINAL  64

typedef __bf16 bf16x8 __attribute__((ext_vector_type(8)));
typedef float  f32x4  __attribute__((ext_vector_type(4)));

#define HGS 264   // hg LDS row stride in bf16 elems (256 + 8 pad)
#define Y1S 520   // Y1 LDS row stride in bf16 elems (512 + 8 pad)

__device__ __forceinline__ float bf2f(unsigned short u) {
  unsigned int x = ((unsigned int)u) << 16;
  float f; __builtin_memcpy(&f, &x, 4); return f;
}
__device__ __forceinline__ unsigned short f2bf(float f) {
  unsigned int x; __builtin_memcpy(&x, &f, 4);
  unsigned int r = x + 0x7FFFu + ((x >> 16) & 1u);
  return (unsigned short)(r >> 16);
}

// ---------------------------------------------------------------------------
// Pre-kernel: convert W_intra_0 (256x512 f32) and W_intra_1 (512x16 f32) to
// bf16 in MFMA B-fragment order. Thread id == SOURCE element -> coalesced
// reads; scattered 2B writes absorbed by L2.
//   B layout (mfma_f32_16x16x32_bf16): n = lane&15, k = (lane>>4)*8 + j
// ---------------------------------------------------------------------------
__global__ void build_wfrag(const float* __restrict__ W0,
                            const float* __restrict__ W1,
                            unsigned short* __restrict__ W0F,
                            unsigned short* __restrict__ W1F) {
  int tid = blockIdx.x * blockDim.x + threadIdx.x;
  if (tid < 131072) {
    int k = tid >> 9, n = tid & 511;
    float v = W0[tid];                       // coalesced
    int k8 = k >> 5, kr = k & 31;
    int j = kr & 7, lhi = kr >> 3;
    int nt = n >> 4, n16 = n & 15;
    int l = lhi * 16 + n16;
    W0F[(((k8 * 32 + nt) * 64) + l) * 8 + j] = f2bf(v);
  } else {
    int t2 = tid - 131072;
    if (t2 < 8192) {
      int k = t2 >> 4, n = t2 & 15;
      float v = W1[t2];                      // coalesced
      int ks = k >> 5, kr = k & 31;
      int j = kr & 7, lhi = kr >> 3;
      int l = lhi * 16 + n;
      W1F[((ks * 64) + l) * 8 + j] = f2bf(v);
    }
  }
}

// ---------------------------------------------------------------------------
// Main fused kernel: TWO blocks per scene (1024 blocks, 512 threads, 4
// blocks/CU). Counters showed the old 512-block version latency-bound
// (HBM 14%, VALU 9%, Mfma 2%, Occ 32%): only 2 serial phase-chains per CU.
// Both blocks of a scene redundantly compute P1..P4 (bit-identical
// arithmetic); each writes 64 of the 128 pedestrians. An XCD-pairing
// swizzle co-locates the two halves of a scene on one XCD so the
// redundant h read is served by the same L2.
// ---------------------------------------------------------------------------
__global__ __launch_bounds__(512, 8) void scene_kernel(
    const float* __restrict__ h,              // (B,256) f32
    const int* __restrict__ sse,              // (S,2) int words
    const int* __restrict__ grp,              // (B,)  int words
    const unsigned short* __restrict__ W0F,   // frag-ordered bf16 W_intra_0
    const unsigned short* __restrict__ W1F,   // frag-ordered bf16 W_intra_1
    const float* __restrict__ Wi0,            // (16,512) f32
    const float* __restrict__ Wi1,            // (512,16) f32
    const float* __restrict__ Wout,           // (32,64) f32
    const float* __restrict__ bout,           // (64,) f32
    float* __restrict__ out)                  // (B,64) f32
{
  __shared__ __align__(16) unsigned short y1[16 * Y1S];   // 16640 B
  __shared__ __align__(16) unsigned short hg[G_GRP * HGS];// 8448 B
  __shared__ __align__(16) float hg2p[8 * 16 * 16];       // 8192 B
  __shared__ __align__(16) float t1v[D_HID];              // 2048 B
  __shared__ int lab[P_PED];
  __shared__ int cnt[G_GRP];
  __shared__ int bad;
  __shared__ unsigned char members[G_GRP][P_PED];
  __shared__ float hg2[G_GRP][D_OUT];
  __shared__ float mvec[D_OUT];
  __shared__ float hiv[D_OUT];
  __shared__ float cvec[D_FINAL];

  const int t = threadIdx.x;
  // XCD-pairing swizzle: HW round-robins blockIdx%8 across XCDs. Map so the
  // two halves of a scene land on the SAME XCD (adjacent slots, same L2):
  //   xcd = bid&7, slot = bid>>3 (0..127); s = xcd*64 + slot/2; half = slot&1
  const int bid  = blockIdx.x;
  const int s    = (bid & 7) * 64 + ((bid >> 3) >> 1);
  const int half = (bid >> 3) & 1;
  const int is64 = (grp[1] == 0) ? 1 : 0;   // labels >=1; int64 high word == 0
  const int start = is64 ? sse[4 * s] : sse[2 * s];
  const int w = t >> 6;                  // wave id 0..7
  const int l = t & 63;                  // lane
  const int m16 = l & 15;                // MFMA row/col within quad
  const int q = l >> 4;                  // quad id

  if (t < G_GRP) cnt[t] = 0;
  if (t == 0) bad = 0;
  __syncthreads();                       // trivial: nothing in flight yet

  // -------- P1: speculative row loads (batch 0), label work overlapped ----
  // Wave w owns rows w+8j (j=0..15): for canonical labels g=p%16 these are
  // exactly the members of groups w (j even) and w+8 (j odd).
  const float* hbase = h + (size_t)start * D_IN + (l << 2);
  f32x4 vbuf[8];
  #pragma unroll
  for (int j = 0; j < 8; ++j)            // 8 independent coalesced dwordx4
    vbuf[j] = *(const f32x4*)(hbase + (size_t)(w + 8 * j) * D_IN);

  int myg = -1;
  if (t < P_PED) {
    int idx = start + t;
    myg = (is64 ? grp[2 * idx] : grp[idx]) - 1;  // overlaps h-load latency
  }
  if (t < P_PED) {
    if (myg != (t & 15)) atomicOr(&bad, 1);      // canonical-pattern check
    int g = myg;
    if (g < 0) g = 0; if (g > G_GRP - 1) g = G_GRP - 1;
    lab[t] = g;
    int slot = atomicAdd(&cnt[g], 1);
    if (slot < P_PED) members[g][slot] = (unsigned char)t;
  }

  // accumulate batch 0, issue+accumulate batch 1 (register-only reduction)
  f32x4 acc0 = {0.f, 0.f, 0.f, 0.f}, acc1 = {0.f, 0.f, 0.f, 0.f};
  #pragma unroll
  for (int j = 0; j < 8; ++j) {
    if (j & 1) acc1 += vbuf[j]; else acc0 += vbuf[j];
  }
  #pragma unroll
  for (int j = 0; j < 8; ++j)
    vbuf[j] = *(const f32x4*)(hbase + (size_t)(w + 8 * (j + 8)) * D_IN);
  #pragma unroll
  for (int j = 0; j < 8; ++j) {
    if (j & 1) acc1 += vbuf[j]; else acc0 += vbuf[j];
  }
  __syncthreads();                       // lab/cnt/members/bad visible

  // -------- P1b: finalize group means -> hg (bf16, padded rows) --------
  {
    int g0 = w, g1 = w + 8;
    if (bad == 0) {
      acc0 *= 0.125f;                    // canonical: every group has 8 rows
      acc1 *= 0.125f;
    } else {
      // general-label fallback: member-driven reload from global (rare path)
      int cn0 = cnt[g0], cn1 = cnt[g1];
      acc0 = (f32x4){0.f, 0.f, 0.f, 0.f};
      acc1 = (f32x4){0.f, 0.f, 0.f, 0.f};
      for (int m = 0; m < cn0; ++m)
        acc0 += *(const f32x4*)(h + (size_t)(start + members[g0][m]) * D_IN + (l << 2));
      for (int m = 0; m < cn1; ++m)
        acc1 += *(const f32x4*)(h + (size_t)(start + members[g1][m]) * D_IN + (l << 2));
      acc0 *= 1.0f / (float)(cn0 > 0 ? cn0 : 1);
      acc1 *= 1.0f / (float)(cn1 > 0 ? cn1 : 1);
    }
    ushort4 o0, o1;
    o0.x = f2bf(acc0[0]); o0.y = f2bf(acc0[1]); o0.z = f2bf(acc0[2]); o0.w = f2bf(acc0[3]);
    o1.x = f2bf(acc1[0]); o1.y = f2bf(acc1[1]); o1.z = f2bf(acc1[2]); o1.w = f2bf(acc1[3]);
    *(ushort4*)&hg[g0 * HGS + (l << 2)] = o0;
    *(ushort4*)&hg[g1 * HGS + (l << 2)] = o1;
  }
  __syncthreads();

  // -------- P2: Y1 = relu(hg @ W0)   (16 x 512), MFMA 16x16x32 bf16 --------
  bf16x8 afr[8];
  #pragma unroll
  for (int k8 = 0; k8 < 8; ++k8)
    afr[k8] = *(const bf16x8*)&hg[m16 * HGS + k8 * 32 + q * 8];

  #pragma unroll
  for (int ntl = 0; ntl < 4; ++ntl) {
    int nt = w * 4 + ntl;
    f32x4 acc = {0.f, 0.f, 0.f, 0.f};
    #pragma unroll
    for (int k8 = 0; k8 < 8; ++k8) {
      bf16x8 bfr = *(const bf16x8*)(W0F + (size_t)(((k8 * 32 + nt) * 64) + l) * 8);
      acc = __builtin_amdgcn_mfma_f32_16x16x32_bf16(afr[k8], bfr, acc, 0, 0, 0);
    }
    #pragma unroll
    for (int r = 0; r < 4; ++r) {
      float v = acc[r];
      v = v > 0.f ? v : 0.f;
      y1[(q * 4 + r) * Y1S + nt * 16 + m16] = f2bf(v);  // row=group, col=hid
    }
  }
  __syncthreads();

  // -------- P3: Hg2 = relu(Y1 @ W1)  (16x16), MFMA, K=512 split over waves --
  {
    f32x4 acc = {0.f, 0.f, 0.f, 0.f};
    #pragma unroll
    for (int kk = 0; kk < 2; ++kk) {
      int ks = w * 2 + kk;
      bf16x8 a2 = *(const bf16x8*)&y1[m16 * Y1S + ks * 32 + q * 8];
      bf16x8 b2 = *(const bf16x8*)(W1F + (size_t)(ks * 64 + l) * 8);
      acc = __builtin_amdgcn_mfma_f32_16x16x32_bf16(a2, b2, acc, 0, 0, 0);
    }
    #pragma unroll
    for (int r = 0; r < 4; ++r)
      hg2p[(w * 16 + (q * 4 + r)) * 16 + m16] = acc[r];
  }
  __syncthreads();
  if (t < 256) {
    int g = t >> 4, n = t & 15;
    float sum = 0.f;
    #pragma unroll
    for (int ww = 0; ww < 8; ++ww) sum += hg2p[(ww * 16 + g) * 16 + n];
    hg2[g][n] = sum > 0.f ? sum : 0.f;
  }
  __syncthreads();

  // -------- P4: inter-group chain (Ai = 1/G makes all rows identical) ------
  if (t < D_OUT) {
    float sm = 0.f;
    #pragma unroll
    for (int g = 0; g < G_GRP; ++g) sm += hg2[g][t];
    mvec[t] = sm * (1.0f / 16.0f);
  }
  __syncthreads();
  {
    float sm = 0.f;
    #pragma unroll
    for (int n = 0; n < D_OUT; ++n) sm += mvec[n] * Wi0[n * D_HID + t];
    t1v[t] = sm > 0.f ? sm : 0.f;
  }
  __syncthreads();
  #pragma unroll
  for (int nn = 0; nn < 2; ++nn) {
    int n = w * 2 + nn;
    float part = 0.f;
    #pragma unroll
    for (int r = 0; r < 8; ++r) {
      int j = l + r * 64;
      part += t1v[j] * Wi1[j * D_OUT + n];
    }
    for (int off = 32; off; off >>= 1) part += __shfl_down(part, off);
    if (l == 0) hiv[n] = part > 0.f ? part : 0.f;
  }
  __syncthreads();
  if (t < D_FINAL) {
    float sm = 0.f;
    #pragma unroll
    for (int n = 0; n < D_OUT; ++n)
      sm += hiv[n] * Wout[(G_GRP + n) * D_FINAL + t];
    cvec[t] = sm;   // inter contribution before 1/cnt[g] scale; no bias
  }
  __syncthreads();

  // -------- P5+P6 fused: this block writes pedestrians [half*64, half*64+64)
  // Same fma chain per (g,c) as the verified fused version -> bit-identical.
  for (int it = 0; it < 2; ++it) {
    int i4 = t + it * 512;          // 1024 float4 items = 64 rows * 16
    int p  = half * 64 + (i4 >> 4);
    int c4 = i4 & 15;
    int g  = lab[p];
    int cn = cnt[g];
    float inv = 1.0f / (float)(cn > 0 ? cn : 1);
    float sm0 = 0.f, sm1 = 0.f, sm2 = 0.f, sm3 = 0.f;
    #pragma unroll
    for (int n = 0; n < D_OUT; ++n) {
      float hv = hg2[g][n];
      const float4 wv = *(const float4*)&Wout[n * D_FINAL + c4 * 4];
      sm0 += hv * wv.x; sm1 += hv * wv.y;
      sm2 += hv * wv.z; sm3 += hv * wv.w;
    }
    float4 v;
    v.x = sm0 + (cvec[c4 * 4 + 0] * inv + bout[c4 * 4 + 0]);
    v.y = sm1 + (cvec[c4 * 4 + 1] * inv + bout[c4 * 4 + 1]);
    v.z = sm2 + (cvec[c4 * 4 + 2] * inv + bout[c4 * 4 + 2]);
    v.w = sm3 + (cvec[c4 * 4 + 3] * inv + bout[c4 * 4 + 3]);
    *(float4*)(out + (size_t)(start + p) * D_FINAL + c4 * 4) = v;
  }
}

extern "C" void kernel_launch(void* const* d_in, const int* in_sizes, int n_in,
                              void* d_out, int out_size, void* d_ws, size_t ws_size,
                              hipStream_t stream) {
  const float* h    = (const float*)d_in[0];
  // d_in[1] = end_pos : unused by the reference
  const int*   sse  = (const int*)d_in[2];
  const int*   grp  = (const int*)d_in[3];
  const float* W0   = (const float*)d_in[4];
  const float* W1   = (const float*)d_in[5];
  const float* Wi0  = (const float*)d_in[6];
  const float* Wi1  = (const float*)d_in[7];
  const float* Wout = (const float*)d_in[8];
  const float* bout = (const float*)d_in[9];

  unsigned short* W0F = (unsigned short*)d_ws;            // 131072 elems
  unsigned short* W1F = (unsigned short*)d_ws + 131072;   //   8192 elems

  build_wfrag<<<544, 256, 0, stream>>>(W0, W1, W0F, W1F);
  scene_kernel<<<2 * S_SCENES, 512, 0, stream>>>(h, sse, grp, W0F, W1F,
                                                 Wi0, Wi1, Wout, bout,
                                                 (float*)d_out);
}

// Round 9
// 149.745 us; speedup vs baseline: 1.0775x; 1.0775x over previous
//
#include <hip/hip_runtime.h>
#include <hip/hip_bf16.h>

// Problem constants (from reference setup_inputs)
#define S_SCENES 512
#define P_PED    128
#define G_GRP    16
#define D_IN     256
#define D_HID    512
#define D_OUT    16
#define D_FINAL  64

typedef __bf16 bf16x8 __attribute__((ext_vector_type(8)));
typedef float  f32x4  __attribute__((ext_vector_type(4)));

#define HGS 264   // hg LDS row stride in bf16 elems (256 + 8 pad)
#define Y1S 520   // Y1 LDS row stride in bf16 elems (512 + 8 pad)

__device__ __forceinline__ float bf2f(unsigned short u) {
  unsigned int x = ((unsigned int)u) << 16;
  float f; __builtin_memcpy(&f, &x, 4); return f;
}
__device__ __forceinline__ unsigned short f2bf(float f) {
  unsigned int x; __builtin_memcpy(&x, &f, 4);
  unsigned int r = x + 0x7FFFu + ((x >> 16) & 1u);
  return (unsigned short)(r >> 16);
}

// ---------------------------------------------------------------------------
// Pre-kernel: convert W_intra_0 (256x512 f32) and W_intra_1 (512x16 f32) to
// bf16 in MFMA B-fragment order.
// ---------------------------------------------------------------------------
__global__ void build_wfrag(const float* __restrict__ W0,
                            const float* __restrict__ W1,
                            unsigned short* __restrict__ W0F,
                            unsigned short* __restrict__ W1F) {
  int tid = blockIdx.x * blockDim.x + threadIdx.x;
  if (tid < 131072) {
    int k = tid >> 9, n = tid & 511;
    float v = W0[tid];                       // coalesced
    int k8 = k >> 5, kr = k & 31;
    int j = kr & 7, lhi = kr >> 3;
    int nt = n >> 4, n16 = n & 15;
    int l = lhi * 16 + n16;
    W0F[(((k8 * 32 + nt) * 64) + l) * 8 + j] = f2bf(v);
  } else {
    int t2 = tid - 131072;
    if (t2 < 8192) {
      int k = t2 >> 4, n = t2 & 15;
      float v = W1[t2];                      // coalesced
      int ks = k >> 5, kr = k & 31;
      int j = kr & 7, lhi = kr >> 3;
      int l = lhi * 16 + n;
      W1F[((ks * 64) + l) * 8 + j] = f2bf(v);
    }
  }
}

// ---------------------------------------------------------------------------
// Main fused kernel: EXACT copy of the verified 129.15us version (round 2).
// ---------------------------------------------------------------------------
__global__ __launch_bounds__(512, 4) void scene_kernel(
    const float* __restrict__ h,              // (B,256) f32
    const int* __restrict__ sse,              // (S,2) int words
    const int* __restrict__ grp,              // (B,)  int words
    const unsigned short* __restrict__ W0F,   // frag-ordered bf16 W_intra_0
    const unsigned short* __restrict__ W1F,   // frag-ordered bf16 W_intra_1
    const float* __restrict__ Wi0,            // (16,512) f32
    const float* __restrict__ Wi1,            // (512,16) f32
    const float* __restrict__ Wout,           // (32,64) f32
    const float* __restrict__ bout,           // (64,) f32
    float* __restrict__ out)                  // (B,64) f32
{
  __shared__ __align__(16) unsigned short y1[16 * Y1S];   // 16640 B
  __shared__ __align__(16) unsigned short hg[G_GRP * HGS];// 8448 B
  __shared__ __align__(16) float hg2p[8 * 16 * 16];       // 8192 B
  __shared__ __align__(16) float t1v[D_HID];              // 2048 B
  __shared__ __align__(16) float orow[16 * D_FINAL];      // 4096 B
  __shared__ int lab[P_PED];
  __shared__ int cnt[G_GRP];
  __shared__ int bad;
  __shared__ unsigned char members[G_GRP][P_PED];
  __shared__ float hg2[G_GRP][D_OUT];
  __shared__ float mvec[D_OUT];
  __shared__ float hiv[D_OUT];
  __shared__ float cvec[D_FINAL];

  const int t = threadIdx.x;
  const int s = blockIdx.x;
  const int is64 = (grp[1] == 0) ? 1 : 0;   // labels >=1; int64 high word == 0
  const int start = is64 ? sse[4 * s] : sse[2 * s];
  const int w = t >> 6;                  // wave id 0..7
  const int l = t & 63;                  // lane
  const int m16 = l & 15;                // MFMA row/col within quad
  const int q = l >> 4;                  // quad id

  if (t < G_GRP) cnt[t] = 0;
  if (t == 0) bad = 0;
  __syncthreads();                       // trivial: nothing in flight yet

  // -------- P1: speculative row loads (batch 0), label work overlapped ----
  const float* hbase = h + (size_t)start * D_IN + (l << 2);
  f32x4 vbuf[8];
  #pragma unroll
  for (int j = 0; j < 8; ++j)            // 8 independent coalesced dwordx4
    vbuf[j] = *(const f32x4*)(hbase + (size_t)(w + 8 * j) * D_IN);

  int myg = -1;
  if (t < P_PED) {
    int idx = start + t;
    myg = (is64 ? grp[2 * idx] : grp[idx]) - 1;  // overlaps h-load latency
  }
  if (t < P_PED) {
    if (myg != (t & 15)) atomicOr(&bad, 1);      // canonical-pattern check
    int g = myg;
    if (g < 0) g = 0; if (g > G_GRP - 1) g = G_GRP - 1;
    lab[t] = g;
    int slot = atomicAdd(&cnt[g], 1);
    if (slot < P_PED) members[g][slot] = (unsigned char)t;
  }

  // accumulate batch 0, issue+accumulate batch 1 (register-only reduction)
  f32x4 acc0 = {0.f, 0.f, 0.f, 0.f}, acc1 = {0.f, 0.f, 0.f, 0.f};
  #pragma unroll
  for (int j = 0; j < 8; ++j) {
    if (j & 1) acc1 += vbuf[j]; else acc0 += vbuf[j];
  }
  #pragma unroll
  for (int j = 0; j < 8; ++j)
    vbuf[j] = *(const f32x4*)(hbase + (size_t)(w + 8 * (j + 8)) * D_IN);
  #pragma unroll
  for (int j = 0; j < 8; ++j) {
    if (j & 1) acc1 += vbuf[j]; else acc0 += vbuf[j];
  }
  __syncthreads();                       // lab/cnt/members/bad visible

  // -------- P1b: finalize group means -> hg (bf16, padded rows) --------
  {
    int g0 = w, g1 = w + 8;
    if (bad == 0) {
      acc0 *= 0.125f;                    // canonical: every group has 8 rows
      acc1 *= 0.125f;
    } else {
      int cn0 = cnt[g0], cn1 = cnt[g1];
      acc0 = (f32x4){0.f, 0.f, 0.f, 0.f};
      acc1 = (f32x4){0.f, 0.f, 0.f, 0.f};
      for (int m = 0; m < cn0; ++m)
        acc0 += *(const f32x4*)(h + (size_t)(start + members[g0][m]) * D_IN + (l << 2));
      for (int m = 0; m < cn1; ++m)
        acc1 += *(const f32x4*)(h + (size_t)(start + members[g1][m]) * D_IN + (l << 2));
      acc0 *= 1.0f / (float)(cn0 > 0 ? cn0 : 1);
      acc1 *= 1.0f / (float)(cn1 > 0 ? cn1 : 1);
    }
    ushort4 o0, o1;
    o0.x = f2bf(acc0[0]); o0.y = f2bf(acc0[1]); o0.z = f2bf(acc0[2]); o0.w = f2bf(acc0[3]);
    o1.x = f2bf(acc1[0]); o1.y = f2bf(acc1[1]); o1.z = f2bf(acc1[2]); o1.w = f2bf(acc1[3]);
    *(ushort4*)&hg[g0 * HGS + (l << 2)] = o0;
    *(ushort4*)&hg[g1 * HGS + (l << 2)] = o1;
  }
  __syncthreads();

  // -------- P2: Y1 = relu(hg @ W0)   (16 x 512), MFMA 16x16x32 bf16 --------
  bf16x8 afr[8];
  #pragma unroll
  for (int k8 = 0; k8 < 8; ++k8)
    afr[k8] = *(const bf16x8*)&hg[m16 * HGS + k8 * 32 + q * 8];

  #pragma unroll
  for (int ntl = 0; ntl < 4; ++ntl) {
    int nt = w * 4 + ntl;
    f32x4 acc = {0.f, 0.f, 0.f, 0.f};
    #pragma unroll
    for (int k8 = 0; k8 < 8; ++k8) {
      bf16x8 bfr = *(const bf16x8*)(W0F + (size_t)(((k8 * 32 + nt) * 64) + l) * 8);
      acc = __builtin_amdgcn_mfma_f32_16x16x32_bf16(afr[k8], bfr, acc, 0, 0, 0);
    }
    #pragma unroll
    for (int r = 0; r < 4; ++r) {
      float v = acc[r];
      v = v > 0.f ? v : 0.f;
      y1[(q * 4 + r) * Y1S + nt * 16 + m16] = f2bf(v);  // row=group, col=hid
    }
  }
  __syncthreads();

  // -------- P3: Hg2 = relu(Y1 @ W1)  (16x16), MFMA, K=512 split over waves --
  {
    f32x4 acc = {0.f, 0.f, 0.f, 0.f};
    #pragma unroll
    for (int kk = 0; kk < 2; ++kk) {
      int ks = w * 2 + kk;
      bf16x8 a2 = *(const bf16x8*)&y1[m16 * Y1S + ks * 32 + q * 8];
      bf16x8 b2 = *(const bf16x8*)(W1F + (size_t)(ks * 64 + l) * 8);
      acc = __builtin_amdgcn_mfma_f32_16x16x32_bf16(a2, b2, acc, 0, 0, 0);
    }
    #pragma unroll
    for (int r = 0; r < 4; ++r)
      hg2p[(w * 16 + (q * 4 + r)) * 16 + m16] = acc[r];
  }
  __syncthreads();
  if (t < 256) {
    int g = t >> 4, n = t & 15;
    float sum = 0.f;
    #pragma unroll
    for (int ww = 0; ww < 8; ++ww) sum += hg2p[(ww * 16 + g) * 16 + n];
    hg2[g][n] = sum > 0.f ? sum : 0.f;
  }
  __syncthreads();

  // -------- P4: inter-group chain (Ai = 1/G makes all rows identical) ------
  if (t < D_OUT) {
    float sm = 0.f;
    #pragma unroll
    for (int g = 0; g < G_GRP; ++g) sm += hg2[g][t];
    mvec[t] = sm * (1.0f / 16.0f);
  }
  __syncthreads();
  {
    float sm = 0.f;
    #pragma unroll
    for (int n = 0; n < D_OUT; ++n) sm += mvec[n] * Wi0[n * D_HID + t];
    t1v[t] = sm > 0.f ? sm : 0.f;
  }
  __syncthreads();
  #pragma unroll
  for (int nn = 0; nn < 2; ++nn) {
    int n = w * 2 + nn;
    float part = 0.f;
    #pragma unroll
    for (int r = 0; r < 8; ++r) {
      int j = l + r * 64;
      part += t1v[j] * Wi1[j * D_OUT + n];
    }
    for (int off = 32; off; off >>= 1) part += __shfl_down(part, off);
    if (l == 0) hiv[n] = part > 0.f ? part : 0.f;
  }
  __syncthreads();
  if (t < D_FINAL) {
    float sm = 0.f;
    #pragma unroll
    for (int n = 0; n < D_OUT; ++n)
      sm += hiv[n] * Wout[(G_GRP + n) * D_FINAL + t];
    cvec[t] = sm;   // inter contribution before 1/cnt[g] scale; no bias
  }
  __syncthreads();

  // -------- P5: 16 distinct output rows --------
  for (int it = 0; it < 2; ++it) {
    int item = t + it * 512;
    int g = item >> 6, c = item & 63;
    float sm = 0.f;
    #pragma unroll
    for (int n = 0; n < D_OUT; ++n)
      sm += hg2[g][n] * Wout[n * D_FINAL + c];
    int cn = cnt[g];
    float inv = 1.0f / (float)(cn > 0 ? cn : 1);
    sm += cvec[c] * inv + bout[c];
    orow[g * D_FINAL + c] = sm;
  }
  __syncthreads();

  // -------- P6: scatter rows to 128 pedestrians (coalesced 16B stores) -----
  for (int it = 0; it < 4; ++it) {
    int i4 = t + it * 512;          // 2048 float4 items = 128 rows * 16
    int p  = i4 >> 4;
    int c4 = i4 & 15;
    int g  = lab[p];
    float4 v = *(const float4*)&orow[g * D_FINAL + c4 * 4];
    *(float4*)(out + (size_t)(start + p) * D_FINAL + c4 * 4) = v;
  }
}

// ---------------------------------------------------------------------------
// PROBE: P2..P6 tail in isolation. Synthesizes hg=0, lab=p%16, cnt=8 (no h
// reads, no P1), runs the EXACT tail phase chain with real W0F/W1F/Wi*/Wout
// traffic, and writes its (meaningless but data-dependent) result to d_ws.
// dur_us - 129.15 = cost of the tail. Same grid/launch-bounds/LDS as scene.
// ---------------------------------------------------------------------------
__global__ __launch_bounds__(512, 4) void probe_tail(
    const unsigned short* __restrict__ W0F,
    const unsigned short* __restrict__ W1F,
    const float* __restrict__ Wi0,
    const float* __restrict__ Wi1,
    const float* __restrict__ Wout,
    const float* __restrict__ bout,
    float* __restrict__ pout)                 // d_ws + 32MB, 16MB region
{
  __shared__ __align__(16) unsigned short y1[16 * Y1S];
  __shared__ __align__(16) unsigned short hg[G_GRP * HGS];
  __shared__ __align__(16) float hg2p[8 * 16 * 16];
  __shared__ __align__(16) float t1v[D_HID];
  __shared__ __align__(16) float orow[16 * D_FINAL];
  __shared__ int lab[P_PED];
  __shared__ int cnt[G_GRP];
  __shared__ float hg2[G_GRP][D_OUT];
  __shared__ float mvec[D_OUT];
  __shared__ float hiv[D_OUT];
  __shared__ float cvec[D_FINAL];

  const int t = threadIdx.x;
  const int s = blockIdx.x;
  const int w = t >> 6;
  const int l = t & 63;
  const int m16 = l & 15;
  const int q = l >> 4;

  // synthesize P1's outputs (no global reads)
  if (t < G_GRP) cnt[t] = 8;
  if (t < P_PED) lab[t] = t & 15;
  for (int i = t; i < 528; i += 512) {   // 528*8 = 4224 ushorts = whole hg
    ushort4 z = {0, 0, 0, 0};
    *(ushort4*)&hg[i * 8] = z;
    *(ushort4*)&hg[i * 8 + 4] = z;
  }
  __syncthreads();

  // -------- P2 (verbatim) --------
  bf16x8 afr[8];
  #pragma unroll
  for (int k8 = 0; k8 < 8; ++k8)
    afr[k8] = *(const bf16x8*)&hg[m16 * HGS + k8 * 32 + q * 8];

  #pragma unroll
  for (int ntl = 0; ntl < 4; ++ntl) {
    int nt = w * 4 + ntl;
    f32x4 acc = {0.f, 0.f, 0.f, 0.f};
    #pragma unroll
    for (int k8 = 0; k8 < 8; ++k8) {
      bf16x8 bfr = *(const bf16x8*)(W0F + (size_t)(((k8 * 32 + nt) * 64) + l) * 8);
      acc = __builtin_amdgcn_mfma_f32_16x16x32_bf16(afr[k8], bfr, acc, 0, 0, 0);
    }
    #pragma unroll
    for (int r = 0; r < 4; ++r) {
      float v = acc[r];
      v = v > 0.f ? v : 0.f;
      y1[(q * 4 + r) * Y1S + nt * 16 + m16] = f2bf(v);
    }
  }
  __syncthreads();

  // -------- P3 (verbatim) --------
  {
    f32x4 acc = {0.f, 0.f, 0.f, 0.f};
    #pragma unroll
    for (int kk = 0; kk < 2; ++kk) {
      int ks = w * 2 + kk;
      bf16x8 a2 = *(const bf16x8*)&y1[m16 * Y1S + ks * 32 + q * 8];
      bf16x8 b2 = *(const bf16x8*)(W1F + (size_t)(ks * 64 + l) * 8);
      acc = __builtin_amdgcn_mfma_f32_16x16x32_bf16(a2, b2, acc, 0, 0, 0);
    }
    #pragma unroll
    for (int r = 0; r < 4; ++r)
      hg2p[(w * 16 + (q * 4 + r)) * 16 + m16] = acc[r];
  }
  __syncthreads();
  if (t < 256) {
    int g = t >> 4, n = t & 15;
    float sum = 0.f;
    #pragma unroll
    for (int ww = 0; ww < 8; ++ww) sum += hg2p[(ww * 16 + g) * 16 + n];
    hg2[g][n] = sum > 0.f ? sum : 0.f;
  }
  __syncthreads();

  // -------- P4 (verbatim) --------
  if (t < D_OUT) {
    float sm = 0.f;
    #pragma unroll
    for (int g = 0; g < G_GRP; ++g) sm += hg2[g][t];
    mvec[t] = sm * (1.0f / 16.0f);
  }
  __syncthreads();
  {
    float sm = 0.f;
    #pragma unroll
    for (int n = 0; n < D_OUT; ++n) sm += mvec[n] * Wi0[n * D_HID + t];
    t1v[t] = sm > 0.f ? sm : 0.f;
  }
  __syncthreads();
  #pragma unroll
  for (int nn = 0; nn < 2; ++nn) {
    int n = w * 2 + nn;
    float part = 0.f;
    #pragma unroll
    for (int r = 0; r < 8; ++r) {
      int j = l + r * 64;
      part += t1v[j] * Wi1[j * D_OUT + n];
    }
    for (int off = 32; off; off >>= 1) part += __shfl_down(part, off);
    if (l == 0) hiv[n] = part > 0.f ? part : 0.f;
  }
  __syncthreads();
  if (t < D_FINAL) {
    float sm = 0.f;
    #pragma unroll
    for (int n = 0; n < D_OUT; ++n)
      sm += hiv[n] * Wout[(G_GRP + n) * D_FINAL + t];
    cvec[t] = sm;
  }
  __syncthreads();

  // -------- P5 (verbatim) --------
  for (int it = 0; it < 2; ++it) {
    int item = t + it * 512;
    int g = item >> 6, c = item & 63;
    float sm = 0.f;
    #pragma unroll
    for (int n = 0; n < D_OUT; ++n)
      sm += hg2[g][n] * Wout[n * D_FINAL + c];
    int cn = cnt[g];
    float inv = 1.0f / (float)(cn > 0 ? cn : 1);
    sm += cvec[c] * inv + bout[c];
    orow[g * D_FINAL + c] = sm;
  }
  __syncthreads();

  // -------- P6: scatter to workspace (same store pattern as scene) --------
  for (int it = 0; it < 4; ++it) {
    int i4 = t + it * 512;
    int p  = i4 >> 4;
    int c4 = i4 & 15;
    int g  = lab[p];
    float4 v = *(const float4*)&orow[g * D_FINAL + c4 * 4];
    *(float4*)(pout + (size_t)(s * P_PED + p) * D_FINAL + c4 * 4) = v;
  }
}

extern "C" void kernel_launch(void* const* d_in, const int* in_sizes, int n_in,
                              void* d_out, int out_size, void* d_ws, size_t ws_size,
                              hipStream_t stream) {
  const float* h    = (const float*)d_in[0];
  // d_in[1] = end_pos : unused by the reference
  const int*   sse  = (const int*)d_in[2];
  const int*   grp  = (const int*)d_in[3];
  const float* W0   = (const float*)d_in[4];
  const float* W1   = (const float*)d_in[5];
  const float* Wi0  = (const float*)d_in[6];
  const float* Wi1  = (const float*)d_in[7];
  const float* Wout = (const float*)d_in[8];
  const float* bout = (const float*)d_in[9];

  unsigned short* W0F = (unsigned short*)d_ws;            // 131072 elems
  unsigned short* W1F = (unsigned short*)d_ws + 131072;   //   8192 elems
  float* pout = (float*)((char*)d_ws + (32u << 20));      // probe sink (16MB)

  build_wfrag<<<544, 256, 0, stream>>>(W0, W1, W0F, W1F);
  scene_kernel<<<S_SCENES, 512, 0, stream>>>(h, sse, grp, W0F, W1F,
                                             Wi0, Wi1, Wout, bout,
                                             (float*)d_out);
  // MEASUREMENT: tail-only probe. dur_us - 129.15 = P2..P6 cost.
  probe_tail<<<S_SCENES, 512, 0, stream>>>(W0F, W1F, Wi0, Wi1, Wout, bout,
                                           pout);
}

// Round 10
// 135.551 us; speedup vs baseline: 1.1903x; 1.1047x over previous
//
#include <hip/hip_runtime.h>
#include <hip/hip_bf16.h>

// Problem constants (from reference setup_inputs)
#define S_SCENES 512
#define P_PED    128
#define G_GRP    16
#define D_IN     256
#define D_HID    512
#define D_OUT    16
#define D_FINAL  64

typedef __bf16 bf16x8 __attribute__((ext_vector_type(8)));
typedef float  f32x4  __attribute__((ext_vector_type(4)));

#define HGS 264   // hg LDS row stride in bf16 elems (256 + 8 pad)
#define Y1S 520   // Y1 LDS row stride in bf16 elems (512 + 8 pad)

__device__ __forceinline__ float bf2f(unsigned short u) {
  unsigned int x = ((unsigned int)u) << 16;
  float f; __builtin_memcpy(&f, &x, 4); return f;
}
__device__ __forceinline__ unsigned short f2bf(float f) {
  unsigned int x; __builtin_memcpy(&x, &f, 4);
  unsigned int r = x + 0x7FFFu + ((x >> 16) & 1u);
  return (unsigned short)(r >> 16);
}

// ---------------------------------------------------------------------------
// Pre-kernel: convert W_intra_0 (256x512 f32) and W_intra_1 (512x16 f32) to
// bf16 in MFMA B-fragment order.
// ---------------------------------------------------------------------------
__global__ void build_wfrag(const float* __restrict__ W0,
                            const float* __restrict__ W1,
                            unsigned short* __restrict__ W0F,
                            unsigned short* __restrict__ W1F) {
  int tid = blockIdx.x * blockDim.x + threadIdx.x;
  if (tid < 131072) {
    int k = tid >> 9, n = tid & 511;
    float v = W0[tid];                       // coalesced
    int k8 = k >> 5, kr = k & 31;
    int j = kr & 7, lhi = kr >> 3;
    int nt = n >> 4, n16 = n & 15;
    int l = lhi * 16 + n16;
    W0F[(((k8 * 32 + nt) * 64) + l) * 8 + j] = f2bf(v);
  } else {
    int t2 = tid - 131072;
    if (t2 < 8192) {
      int k = t2 >> 4, n = t2 & 15;
      float v = W1[t2];                      // coalesced
      int ks = k >> 5, kr = k & 31;
      int j = kr & 7, lhi = kr >> 3;
      int l = lhi * 16 + n;
      W1F[((ks * 64) + l) * 8 + j] = f2bf(v);
    }
  }
}

// ---------------------------------------------------------------------------
// Main fused kernel: TWO SCENES per block (256 blocks, 512 threads).
// The probe (r9) pinned the cost: P1 ~10us (HBM floor) + tail ~19us with all
// pipes <16% busy -> the tail is barrier/L2-serialization. Batching 2 scenes
// per block halves barriers/scene AND reuses every W0F/W1F/Wi0/Wi1 load for
// two MFMA/fma chains (W0F traffic 134->67MB). Per-scene arithmetic order is
// verbatim from the verified kernel -> bit-identical output.
// ---------------------------------------------------------------------------
__global__ __launch_bounds__(512, 2) void scene_kernel(
    const float* __restrict__ h,              // (B,256) f32
    const int* __restrict__ sse,              // (S,2) int words
    const int* __restrict__ grp,              // (B,)  int words
    const unsigned short* __restrict__ W0F,   // frag-ordered bf16 W_intra_0
    const unsigned short* __restrict__ W1F,   // frag-ordered bf16 W_intra_1
    const float* __restrict__ Wi0,            // (16,512) f32
    const float* __restrict__ Wi1,            // (512,16) f32
    const float* __restrict__ Wout,           // (32,64) f32
    const float* __restrict__ bout,           // (64,) f32
    float* __restrict__ out)                  // (B,64) f32
{
  __shared__ __align__(16) unsigned short y1[2 * 16 * Y1S];   // 33280 B
  __shared__ __align__(16) unsigned short hg[2 * G_GRP * HGS];// 16896 B
  __shared__ __align__(16) float hg2p[2 * 8 * 16 * 16];       // 16384 B
  __shared__ __align__(16) float t1v[2 * D_HID];              // 4096 B
  __shared__ int lab[2][P_PED];
  __shared__ int cnt[2][G_GRP];
  __shared__ int bad;
  __shared__ unsigned char members[2][G_GRP][P_PED];
  __shared__ float hg2[2][G_GRP][D_OUT];
  __shared__ float mvec[2][D_OUT];
  __shared__ float hiv[2][D_OUT];
  __shared__ float cvec[2][D_FINAL];

  const int t = threadIdx.x;
  const int sA = blockIdx.x * 2, sB = sA + 1;
  const int is64 = (grp[1] == 0) ? 1 : 0;   // labels >=1; int64 high word == 0
  const int stA = is64 ? sse[4 * sA] : sse[2 * sA];
  const int stB = is64 ? sse[4 * sB] : sse[2 * sB];
  const int w = t >> 6;                  // wave id 0..7
  const int l = t & 63;                  // lane
  const int m16 = l & 15;                // MFMA row/col within quad
  const int q = l >> 4;                  // quad id

  if (t < 32) cnt[t >> 4][t & 15] = 0;
  if (t == 0) bad = 0;
  __syncthreads();                       // trivial: nothing in flight yet

  // -------- P1: dual-buffered speculative loads for both scenes ----------
  // Wave w owns rows w+8j; canonical labels g=p%16 -> groups w (j even) and
  // w+8 (j odd). Order per scene identical to the verified kernel.
  const float* hbA = h + (size_t)stA * D_IN + (l << 2);
  const float* hbB = h + (size_t)stB * D_IN + (l << 2);
  f32x4 vx[8], vy[8];
  #pragma unroll
  for (int j = 0; j < 8; ++j)            // scene A batch 0
    vx[j] = *(const f32x4*)(hbA + (size_t)(w + 8 * j) * D_IN);
  #pragma unroll
  for (int j = 0; j < 8; ++j)            // scene A batch 1
    vy[j] = *(const f32x4*)(hbA + (size_t)(w + 64 + 8 * j) * D_IN);

  // labels for both scenes (overlaps h-load latency)
  if (t < 256) {
    int sc = t >> 7, p = t & 127;
    int idx = (sc ? stB : stA) + p;
    int myg = (is64 ? grp[2 * idx] : grp[idx]) - 1;
    if (myg != (p & 15)) atomicOr(&bad, 1);      // canonical-pattern check
    int g = myg;
    if (g < 0) g = 0; if (g > G_GRP - 1) g = G_GRP - 1;
    lab[sc][p] = g;
    int slot = atomicAdd(&cnt[sc][g], 1);
    if (slot < P_PED) members[sc][g][slot] = (unsigned char)p;
  }

  f32x4 aA0 = {0.f,0.f,0.f,0.f}, aA1 = {0.f,0.f,0.f,0.f};
  f32x4 aB0 = {0.f,0.f,0.f,0.f}, aB1 = {0.f,0.f,0.f,0.f};
  #pragma unroll
  for (int j = 0; j < 8; ++j) {          // acc A0 (consumes vx)
    if (j & 1) aA1 += vx[j]; else aA0 += vx[j];
  }
  #pragma unroll
  for (int j = 0; j < 8; ++j)            // scene B batch 0 -> vx
    vx[j] = *(const f32x4*)(hbB + (size_t)(w + 8 * j) * D_IN);
  #pragma unroll
  for (int j = 0; j < 8; ++j) {          // acc A1 (consumes vy)
    if (j & 1) aA1 += vy[j]; else aA0 += vy[j];
  }
  #pragma unroll
  for (int j = 0; j < 8; ++j)            // scene B batch 1 -> vy
    vy[j] = *(const f32x4*)(hbB + (size_t)(w + 64 + 8 * j) * D_IN);
  #pragma unroll
  for (int j = 0; j < 8; ++j) {          // acc B0
    if (j & 1) aB1 += vx[j]; else aB0 += vx[j];
  }
  #pragma unroll
  for (int j = 0; j < 8; ++j) {          // acc B1
    if (j & 1) aB1 += vy[j]; else aB0 += vy[j];
  }
  __syncthreads();                       // lab/cnt/members/bad visible

  // -------- P1b: finalize group means -> hg (bf16, padded rows) --------
  {
    int g0 = w, g1 = w + 8;
    if (bad == 0) {
      aA0 *= 0.125f; aA1 *= 0.125f;      // canonical: every group has 8 rows
      aB0 *= 0.125f; aB1 *= 0.125f;
    } else {
      // general-label fallback: member-driven reload from global (rare path)
      #pragma unroll
      for (int sc = 0; sc < 2; ++sc) {
        const float* hb = sc ? hbB : hbA;
        const int st = sc ? stB : stA; (void)st;
        int cn0 = cnt[sc][g0], cn1 = cnt[sc][g1];
        f32x4 a0 = {0.f,0.f,0.f,0.f}, a1 = {0.f,0.f,0.f,0.f};
        for (int m = 0; m < cn0; ++m)
          a0 += *(const f32x4*)(hb + (size_t)members[sc][g0][m] * D_IN);
        for (int m = 0; m < cn1; ++m)
          a1 += *(const f32x4*)(hb + (size_t)members[sc][g1][m] * D_IN);
        a0 *= 1.0f / (float)(cn0 > 0 ? cn0 : 1);
        a1 *= 1.0f / (float)(cn1 > 0 ? cn1 : 1);
        if (sc == 0) { aA0 = a0; aA1 = a1; } else { aB0 = a0; aB1 = a1; }
      }
    }
    ushort4 oA0, oA1, oB0, oB1;
    oA0.x = f2bf(aA0[0]); oA0.y = f2bf(aA0[1]); oA0.z = f2bf(aA0[2]); oA0.w = f2bf(aA0[3]);
    oA1.x = f2bf(aA1[0]); oA1.y = f2bf(aA1[1]); oA1.z = f2bf(aA1[2]); oA1.w = f2bf(aA1[3]);
    oB0.x = f2bf(aB0[0]); oB0.y = f2bf(aB0[1]); oB0.z = f2bf(aB0[2]); oB0.w = f2bf(aB0[3]);
    oB1.x = f2bf(aB1[0]); oB1.y = f2bf(aB1[1]); oB1.z = f2bf(aB1[2]); oB1.w = f2bf(aB1[3]);
    *(ushort4*)&hg[g0 * HGS + (l << 2)] = oA0;
    *(ushort4*)&hg[g1 * HGS + (l << 2)] = oA1;
    *(ushort4*)&hg[G_GRP * HGS + g0 * HGS + (l << 2)] = oB0;
    *(ushort4*)&hg[G_GRP * HGS + g1 * HGS + (l << 2)] = oB1;
  }
  __syncthreads();

  // -------- P2: Y1 = relu(hg @ W0), both scenes share every W0F load ------
  bf16x8 afrA[8], afrB[8];
  #pragma unroll
  for (int k8 = 0; k8 < 8; ++k8) {
    afrA[k8] = *(const bf16x8*)&hg[m16 * HGS + k8 * 32 + q * 8];
    afrB[k8] = *(const bf16x8*)&hg[G_GRP * HGS + m16 * HGS + k8 * 32 + q * 8];
  }

  #pragma unroll
  for (int ntl = 0; ntl < 4; ++ntl) {
    int nt = w * 4 + ntl;
    f32x4 accA = {0.f,0.f,0.f,0.f}, accB = {0.f,0.f,0.f,0.f};
    #pragma unroll
    for (int k8 = 0; k8 < 8; ++k8) {
      bf16x8 bfr = *(const bf16x8*)(W0F + (size_t)(((k8 * 32 + nt) * 64) + l) * 8);
      accA = __builtin_amdgcn_mfma_f32_16x16x32_bf16(afrA[k8], bfr, accA, 0, 0, 0);
      accB = __builtin_amdgcn_mfma_f32_16x16x32_bf16(afrB[k8], bfr, accB, 0, 0, 0);
    }
    #pragma unroll
    for (int r = 0; r < 4; ++r) {
      float vA = accA[r]; vA = vA > 0.f ? vA : 0.f;
      float vB = accB[r]; vB = vB > 0.f ? vB : 0.f;
      y1[(q * 4 + r) * Y1S + nt * 16 + m16] = f2bf(vA);
      y1[16 * Y1S + (q * 4 + r) * Y1S + nt * 16 + m16] = f2bf(vB);
    }
  }
  __syncthreads();

  // -------- P3: Hg2 = relu(Y1 @ W1), W1F fragments shared ------------------
  {
    bf16x8 b2k0 = *(const bf16x8*)(W1F + (size_t)((w * 2 + 0) * 64 + l) * 8);
    bf16x8 b2k1 = *(const bf16x8*)(W1F + (size_t)((w * 2 + 1) * 64 + l) * 8);
    #pragma unroll
    for (int sc = 0; sc < 2; ++sc) {
      f32x4 acc = {0.f,0.f,0.f,0.f};
      bf16x8 a20 = *(const bf16x8*)&y1[sc * 16 * Y1S + m16 * Y1S + (w * 2 + 0) * 32 + q * 8];
      acc = __builtin_amdgcn_mfma_f32_16x16x32_bf16(a20, b2k0, acc, 0, 0, 0);
      bf16x8 a21 = *(const bf16x8*)&y1[sc * 16 * Y1S + m16 * Y1S + (w * 2 + 1) * 32 + q * 8];
      acc = __builtin_amdgcn_mfma_f32_16x16x32_bf16(a21, b2k1, acc, 0, 0, 0);
      #pragma unroll
      for (int r = 0; r < 4; ++r)
        hg2p[sc * 2048 + (w * 16 + (q * 4 + r)) * 16 + m16] = acc[r];
    }
  }
  __syncthreads();
  {
    int sc = t >> 8, tt = t & 255;       // all 512 threads active
    int g = tt >> 4, n = tt & 15;
    float sum = 0.f;
    #pragma unroll
    for (int ww = 0; ww < 8; ++ww) sum += hg2p[sc * 2048 + (ww * 16 + g) * 16 + n];
    hg2[sc][g][n] = sum > 0.f ? sum : 0.f;
  }
  __syncthreads();

  // -------- P4: inter-group chain, Wi0/Wi1 loads shared across scenes ------
  if (t < 32) {
    int sc = t >> 4, n = t & 15;
    float sm = 0.f;
    #pragma unroll
    for (int g = 0; g < G_GRP; ++g) sm += hg2[sc][g][n];
    mvec[sc][n] = sm * (1.0f / 16.0f);
  }
  __syncthreads();
  {
    float smA = 0.f, smB = 0.f;
    #pragma unroll
    for (int n = 0; n < D_OUT; ++n) {
      float wv = Wi0[n * D_HID + t];
      smA += mvec[0][n] * wv;
      smB += mvec[1][n] * wv;
    }
    t1v[t] = smA > 0.f ? smA : 0.f;
    t1v[D_HID + t] = smB > 0.f ? smB : 0.f;
  }
  __syncthreads();
  #pragma unroll
  for (int nn = 0; nn < 2; ++nn) {
    int n = w * 2 + nn;
    float pA = 0.f, pB = 0.f;
    #pragma unroll
    for (int r = 0; r < 8; ++r) {
      int j = l + r * 64;
      float wv = Wi1[j * D_OUT + n];
      pA += t1v[j] * wv;
      pB += t1v[D_HID + j] * wv;
    }
    for (int off = 32; off; off >>= 1) pA += __shfl_down(pA, off);
    for (int off = 32; off; off >>= 1) pB += __shfl_down(pB, off);
    if (l == 0) {
      hiv[0][n] = pA > 0.f ? pA : 0.f;
      hiv[1][n] = pB > 0.f ? pB : 0.f;
    }
  }
  __syncthreads();
  if (t < 128) {
    int sc = t >> 6, c = t & 63;
    float sm = 0.f;
    #pragma unroll
    for (int n = 0; n < D_OUT; ++n)
      sm += hiv[sc][n] * Wout[(G_GRP + n) * D_FINAL + c];
    cvec[sc][c] = sm;  // inter contribution before 1/cnt[g] scale; no bias
  }
  __syncthreads();

  // -------- P5+P6 fused (verified bit-exact): both scenes, 4096 float4 -----
  #pragma unroll
  for (int it = 0; it < 8; ++it) {
    int i  = t + it * 512;          // 4096 items = 2 scenes * 128 rows * 16
    int sc = i >> 11;
    int i2 = i & 2047;
    int p  = i2 >> 4;
    int c4 = i2 & 15;
    int g  = lab[sc][p];
    int cn = cnt[sc][g];
    float inv = 1.0f / (float)(cn > 0 ? cn : 1);
    float sm0 = 0.f, sm1 = 0.f, sm2 = 0.f, sm3 = 0.f;
    #pragma unroll
    for (int n = 0; n < D_OUT; ++n) {
      float hv = hg2[sc][g][n];
      const float4 wv = *(const float4*)&Wout[n * D_FINAL + c4 * 4];
      sm0 += hv * wv.x; sm1 += hv * wv.y;
      sm2 += hv * wv.z; sm3 += hv * wv.w;
    }
    float4 v;
    v.x = sm0 + (cvec[sc][c4 * 4 + 0] * inv + bout[c4 * 4 + 0]);
    v.y = sm1 + (cvec[sc][c4 * 4 + 1] * inv + bout[c4 * 4 + 1]);
    v.z = sm2 + (cvec[sc][c4 * 4 + 2] * inv + bout[c4 * 4 + 2]);
    v.w = sm3 + (cvec[sc][c4 * 4 + 3] * inv + bout[c4 * 4 + 3]);
    int st = sc ? stB : stA;
    *(float4*)(out + (size_t)(st + p) * D_FINAL + c4 * 4) = v;
  }
}

extern "C" void kernel_launch(void* const* d_in, const int* in_sizes, int n_in,
                              void* d_out, int out_size, void* d_ws, size_t ws_size,
                              hipStream_t stream) {
  const float* h    = (const float*)d_in[0];
  // d_in[1] = end_pos : unused by the reference
  const int*   sse  = (const int*)d_in[2];
  const int*   grp  = (const int*)d_in[3];
  const float* W0   = (const float*)d_in[4];
  const float* W1   = (const float*)d_in[5];
  const float* Wi0  = (const float*)d_in[6];
  const float* Wi1  = (const float*)d_in[7];
  const float* Wout = (const float*)d_in[8];
  const float* bout = (const float*)d_in[9];

  unsigned short* W0F = (unsigned short*)d_ws;            // 131072 elems
  unsigned short* W1F = (unsigned short*)d_ws + 131072;   //   8192 elems

  build_wfrag<<<544, 256, 0, stream>>>(W0, W1, W0F, W1F);
  scene_kernel<<<S_SCENES / 2, 512, 0, stream>>>(h, sse, grp, W0F, W1F,
                                                 Wi0, Wi1, Wout, bout,
                                                 (float*)d_out);
}